// Round 1
// baseline (61.607 us; speedup 1.0000x reference)
//
#include <hip/hip_runtime.h>

#define POOLED_H 7
#define POOLED_W 7
#define OUT_DIM 10
#define GRP 7
#define CH (OUT_DIM * GRP * GRP)   // 490
#define FH 128
#define FW 128
#define SPATIAL_SCALE 0.0625f

// One thread per output element (r, c, ph, pw).
__global__ void psroi_align_kernel(const float* __restrict__ feat,
                                   const float* __restrict__ rois,
                                   float* __restrict__ out,
                                   int total) {
    int idx = blockIdx.x * blockDim.x + threadIdx.x;
    if (idx >= total) return;

    int pw = idx % POOLED_W;
    int ph = (idx / POOLED_W) % POOLED_H;
    int c  = (idx / (POOLED_W * POOLED_H)) % OUT_DIM;
    int r  = idx / (POOLED_W * POOLED_H * OUT_DIM);

    const float* roi = rois + (size_t)r * 5;
    int   b   = (int)roi[0];
    float x1  = roi[1] * SPATIAL_SCALE;
    float y1  = roi[2] * SPATIAL_SCALE;
    float x2  = roi[3] * SPATIAL_SCALE;
    float y2  = roi[4] * SPATIAL_SCALE;

    float roi_w = fmaxf(x2 - x1, 0.1f);
    float roi_h = fmaxf(y2 - y1, 0.1f);
    float bin_w = roi_w / (float)POOLED_W;
    float bin_h = roi_h / (float)POOLED_H;

    // gh = ph, gw = pw on this config (GROUP_SIZE == POOLED)
    int c_in = c * (GRP * GRP) + ph * GRP + pw;
    const float* fp = feat + ((size_t)b * CH + (size_t)c_in) * (FH * FW);

    float acc = 0.0f;
#pragma unroll
    for (int iy = 0; iy < 2; ++iy) {
        float sy = ((float)iy + 0.5f) * 0.5f;
        float y  = y1 + ((float)ph + sy) * bin_h;
        y = fminf(fmaxf(y, 0.0f), (float)(FH - 1));
        int   y0 = (int)floorf(y);
        float ly = y - (float)y0;
        int   yB = min(y0 + 1, FH - 1);
#pragma unroll
        for (int ix = 0; ix < 2; ++ix) {
            float sx = ((float)ix + 0.5f) * 0.5f;
            float x  = x1 + ((float)pw + sx) * bin_w;
            x = fminf(fmaxf(x, 0.0f), (float)(FW - 1));
            int   x0 = (int)floorf(x);
            float lx = x - (float)x0;
            int   xB = min(x0 + 1, FW - 1);

            float v00 = fp[y0 * FW + x0];
            float v01 = fp[y0 * FW + xB];
            float v10 = fp[yB * FW + x0];
            float v11 = fp[yB * FW + xB];

            float top = v00 + (v01 - v00) * lx;
            float bot = v10 + (v11 - v10) * lx;
            acc += top + (bot - top) * ly;
        }
    }
    out[idx] = acc * 0.25f;
}

extern "C" void kernel_launch(void* const* d_in, const int* in_sizes, int n_in,
                              void* d_out, int out_size, void* d_ws, size_t ws_size,
                              hipStream_t stream) {
    const float* feat = (const float*)d_in[0];
    const float* rois = (const float*)d_in[1];
    float* out = (float*)d_out;

    int total = out_size;  // 2048 * 10 * 7 * 7
    int block = 256;
    int grid = (total + block - 1) / block;
    psroi_align_kernel<<<grid, block, 0, stream>>>(feat, rois, out, total);
}

// Round 2
// 45.214 us; speedup vs baseline: 1.3626x; 1.3626x over previous
//
#include <hip/hip_runtime.h>

#define FH 128
#define FW 128
#define CPLANE 490          // 10 * 7 * 7 input channels, == bins per roi
#define SSCALE 0.0625f

// 4 lanes per output bin: lane sub = (iy<<1)|ix picks one of the 2x2 samples.
// blockIdx.y = roi index (uniform per block -> roi params land in SGPRs).
__global__ __launch_bounds__(256) void psroi_align4(const float* __restrict__ feat,
                                                    const float* __restrict__ rois,
                                                    float* __restrict__ out) {
    const int r = blockIdx.y;
    const int lane_in_roi = blockIdx.x * 256 + threadIdx.x;   // 0..2047
    const int rem = lane_in_roi >> 2;                         // bin within roi == c_in
    if (rem >= CPLANE) return;
    const int sub = lane_in_roi & 3;
    const int iy = sub >> 1;
    const int ix = sub & 1;

    const int t7 = rem / 7;            // c*7 + ph
    const int pw = rem - t7 * 7;
    const int ph = t7 % 7;

    const float* roi = rois + (size_t)r * 5;
    const int   b  = (int)roi[0];
    const float x1 = roi[1] * SSCALE;
    const float y1 = roi[2] * SSCALE;
    const float x2 = roi[3] * SSCALE;
    const float y2 = roi[4] * SSCALE;
    const float bin_w = fmaxf(x2 - x1, 0.1f) / 7.0f;
    const float bin_h = fmaxf(y2 - y1, 0.1f) / 7.0f;

    // sample position
    const float sy = 0.25f + 0.5f * (float)iy;
    const float sx = 0.25f + 0.5f * (float)ix;

    float y = y1 + ((float)ph + sy) * bin_h;
    y = fminf(fmaxf(y, 0.0f), 127.0f);
    float y0f = floorf(y);
    int   y0  = (int)y0f;
    float ly  = y - y0f;
    if (y0 > 126) { y0 = 126; ly = 1.0f; }   // y==127.0 exactly -> weight all on row 127

    float x = x1 + ((float)pw + sx) * bin_w;
    x = fminf(fmaxf(x, 0.0f), 127.0f);
    float x0f = floorf(x);
    int   x0  = (int)x0f;
    float lx  = x - x0f;
    if (x0 > 126) { x0 = 126; lx = 1.0f; }

    const float* fp = feat + ((size_t)b * CPLANE + (size_t)rem) * (FH * FW)
                            + y0 * FW + x0;
    const float v00 = fp[0];
    const float v01 = fp[1];
    const float v10 = fp[FW];
    const float v11 = fp[FW + 1];

    const float top = v00 + (v01 - v00) * lx;
    const float bot = v10 + (v11 - v10) * lx;
    float val = top + (bot - top) * ly;

    // reduce the 4 samples of this bin and average
    val += __shfl_xor(val, 1);
    val += __shfl_xor(val, 2);
    if (sub == 0) out[(size_t)r * CPLANE + rem] = val * 0.25f;
}

extern "C" void kernel_launch(void* const* d_in, const int* in_sizes, int n_in,
                              void* d_out, int out_size, void* d_ws, size_t ws_size,
                              hipStream_t stream) {
    const float* feat = (const float*)d_in[0];
    const float* rois = (const float*)d_in[1];
    float* out = (float*)d_out;

    const int R = in_sizes[1] / 5;                 // 2048
    dim3 grid((CPLANE * 4 + 255) / 256, R);        // (8, 2048)
    psroi_align4<<<grid, 256, 0, stream>>>(feat, rois, out);
}

// Round 3
// 44.985 us; speedup vs baseline: 1.3695x; 1.0051x over previous
//
#include <hip/hip_runtime.h>

#define FH 128
#define FW 128
#define CPLANE 490          // 10 * 7 * 7 input channels == bins per roi
#define SSCALE 0.0625f

// 4 lanes per output bin: lane sub = (iy<<1)|ix picks one of the 2x2 samples.
// blockIdx.y = roi index (uniform per block -> roi params in SGPRs).
// Each lane loads its two corner rows as 8B packets (global_load_dwordx2).
__global__ __launch_bounds__(256) void psroi_align4(const float* __restrict__ feat,
                                                    const float* __restrict__ rois,
                                                    float* __restrict__ out) {
    const int r = blockIdx.y;
    const int lane_in_roi = blockIdx.x * 256 + threadIdx.x;   // 0..2047
    const int rem = lane_in_roi >> 2;                         // bin within roi == c_in
    if (rem >= CPLANE) return;
    const int sub = lane_in_roi & 3;
    const int iy = sub >> 1;
    const int ix = sub & 1;

    const int t7 = rem / 7;            // c*7 + ph
    const int pw = rem - t7 * 7;
    const int ph = t7 % 7;

    const float* roi = rois + (size_t)r * 5;
    const int   b  = (int)roi[0];
    const float x1 = roi[1] * SSCALE;
    const float y1 = roi[2] * SSCALE;
    const float x2 = roi[3] * SSCALE;
    const float y2 = roi[4] * SSCALE;
    const float bin_w = fmaxf(x2 - x1, 0.1f) / 7.0f;
    const float bin_h = fmaxf(y2 - y1, 0.1f) / 7.0f;

    const float sy = 0.25f + 0.5f * (float)iy;
    const float sx = 0.25f + 0.5f * (float)ix;

    float y = y1 + ((float)ph + sy) * bin_h;
    y = fminf(fmaxf(y, 0.0f), 127.0f);
    float y0f = floorf(y);
    int   y0  = (int)y0f;
    float ly  = y - y0f;
    if (y0 > 126) { y0 = 126; ly = 1.0f; }   // y==127.0 -> full weight on row 127

    float x = x1 + ((float)pw + sx) * bin_w;
    x = fminf(fmaxf(x, 0.0f), 127.0f);
    float x0f = floorf(x);
    int   x0  = (int)x0f;
    float lx  = x - x0f;
    if (x0 > 126) { x0 = 126; lx = 1.0f; }

    const float* fp = feat + ((size_t)b * CPLANE + (size_t)rem) * (FH * FW)
                            + y0 * FW + x0;

    // 8B packet loads: (v00,v01) and (v10,v11) are contiguous and in-bounds.
    float2 top2, bot2;
    __builtin_memcpy(&top2, fp,      sizeof(float2));
    __builtin_memcpy(&bot2, fp + FW, sizeof(float2));

    const float top = top2.x + (top2.y - top2.x) * lx;
    const float bot = bot2.x + (bot2.y - bot2.x) * lx;
    float val = top + (bot - top) * ly;

    // reduce the 4 samples of this bin and average
    val += __shfl_xor(val, 1);
    val += __shfl_xor(val, 2);
    if (sub == 0) out[(size_t)r * CPLANE + rem] = val * 0.25f;
}

extern "C" void kernel_launch(void* const* d_in, const int* in_sizes, int n_in,
                              void* d_out, int out_size, void* d_ws, size_t ws_size,
                              hipStream_t stream) {
    const float* feat = (const float*)d_in[0];
    const float* rois = (const float*)d_in[1];
    float* out = (float*)d_out;

    const int R = in_sizes[1] / 5;                 // 2048
    dim3 grid((CPLANE * 4 + 255) / 256, R);        // (8, 2048)
    psroi_align4<<<grid, 256, 0, stream>>>(feat, rois, out);
}